// Round 4
// baseline (443.284 us; speedup 1.0000x reference)
//
#include <hip/hip_runtime.h>
#include <math.h>

#define UNITS 100000
#define BATCH 512
#define DIM 512
#define BN 32
#define NBLK (UNITS / BN)              /* 3125, exact */
#define SCALE 64.0f
#define COS_M2 0.87758256189037271612f /* cos(0.5) */
#define SIN_M2 0.47942553860420300027f /* sin(0.5) */
#define LOG2E  1.44269504088896340736f
#define SHIFT64 (64.0f * LOG2E)

typedef _Float16 half8 __attribute__((ext_vector_type(8)));
typedef float floatx4 __attribute__((ext_vector_type(4)));

// ---------------- Kernel 1: row-normalize inputs -> fragment-ordered fp16 A2 (x64) ----
__global__ void norm_emb_k(const float* __restrict__ inp, _Float16* __restrict__ A2) {
    const int row = blockIdx.x;
    const int lane = threadIdx.x;             // 64 threads = 1 wave
    const float* rp = inp + row * DIM + lane * 8;
    float v[8];
#pragma unroll
    for (int j = 0; j < 8; ++j) v[j] = rp[j];
    float ss = 0.f;
#pragma unroll
    for (int j = 0; j < 8; ++j) ss += v[j] * v[j];
#pragma unroll
    for (int off = 32; off > 0; off >>= 1) ss += __shfl_xor(ss, off);
    const float inv = SCALE / sqrtf(ss);      // fold s=64 into A
    half8 h;
#pragma unroll
    for (int j = 0; j < 8; ++j) h[j] = (_Float16)(v[j] * inv);
    const int idx = ((((row >> 4) * 16 + (lane >> 2)) * 64) + (row & 15) + 16 * (lane & 3)) * 8;
    *(half8*)(A2 + idx) = h;
}

// ---------------- Kernels 2&5: fused GEMM + margin + exp; PASS1 sums, PASS2 writes ----
template<int PASS>
__global__ __launch_bounds__(512, 6) void pass_k(
    const float* __restrict__ w, const _Float16* __restrict__ A2,
    const int* __restrict__ label, float* __restrict__ cninv,
    const float* __restrict__ srow, float* __restrict__ psum,
    float* __restrict__ out) {
    __shared__ _Float16 Bt[64 * 32 * 8];     // [kg][c'][k&7], 32KB, XOR-swizzled units
    __shared__ float scratch[8][33];
    __shared__ float cninv_s[32];

    const int t = threadIdx.x;
    const int blk = blockIdx.x;
    const int c0 = blk * BN;
    const int w8 = t >> 6;                   // wave 0..7
    const int lane = t & 63;
    const int r8 = lane >> 3;                // 0..7
    const int q = lane & 7;                  // col quad 0..7
    const int kg0 = w8 * 8 + r8;             // this thread's kg for staging

    // ---- staging: 8 coalesced dwordx4 loads (k-consecutive group), 4 b128 LDS writes -
    floatx4 v[8];
    const float* wp = w + (size_t)(kg0 * 8) * UNITS + c0 + 4 * q;
#pragma unroll
    for (int i = 0; i < 8; ++i) v[i] = *(const floatx4*)(wp + (size_t)i * UNITS);

    float sq[4] = {0.f, 0.f, 0.f, 0.f};
#pragma unroll
    for (int e = 0; e < 4; ++e) {
        half8 h;
#pragma unroll
        for (int i = 0; i < 8; ++i) {
            const float x = v[i][e];
            if (PASS == 1) sq[e] += x * x;
            h[i] = (_Float16)x;
        }
        const int cu = (4 * q + e) ^ (kg0 & 7);   // XOR-swizzle 16B units
        *(half8*)&Bt[(kg0 * 32 + cu) * 8] = h;
    }

    if (PASS == 1) {
        // reduce col sq-sums over r8 lanes (xor 8,16,32), then over waves via LDS
#pragma unroll
        for (int e = 0; e < 4; ++e) {
            sq[e] += __shfl_xor(sq[e], 8);
            sq[e] += __shfl_xor(sq[e], 16);
            sq[e] += __shfl_xor(sq[e], 32);
        }
        if (lane < 8) {
#pragma unroll
            for (int e = 0; e < 4; ++e) scratch[w8][4 * q + e] = sq[e];
        }
    }
    __syncthreads();
    if (PASS == 1) {
        if (t < 32) {
            float s = 0.f;
#pragma unroll
            for (int g = 0; g < 8; ++g) s += scratch[g][t];
            const float r = rsqrtf(s);
            cninv_s[t] = r;
            cninv[c0 + t] = r;
        }
        __syncthreads();
    }

    // ---- barrier-free MFMA loop ----
    const int colg = lane & 15;
    const int rowg = lane >> 4;

    floatx4 acc[4][2];
#pragma unroll
    for (int mf = 0; mf < 4; ++mf)
#pragma unroll
        for (int nf = 0; nf < 2; ++nf) acc[mf][nf] = (floatx4){0.f, 0.f, 0.f, 0.f};

#pragma unroll 4
    for (int ks = 0; ks < 16; ++ks) {
        const int kgr = ks * 4 + rowg;
        half8 b[2];
#pragma unroll
        for (int nf = 0; nf < 2; ++nf) {
            const int cu = (nf * 16 + colg) ^ (kgr & 7);
            b[nf] = *(const half8*)&Bt[(kgr * 32 + cu) * 8];
        }
#pragma unroll
        for (int mf = 0; mf < 4; ++mf) {
            const half8 a = *(const half8*)(A2 + (((w8 * 4 + mf) * 16 + ks) * 64 + lane) * 8);
            acc[mf][0] = __builtin_amdgcn_mfma_f32_16x16x32_f16(a, b[0], acc[mf][0], 0, 0, 0);
            acc[mf][1] = __builtin_amdgcn_mfma_f32_16x16x32_f16(a, b[1], acc[mf][1], 0, 0, 0);
        }
    }

    // ---- epilogue ----
    float cn[2];
    if (PASS == 1) { cn[0] = cninv_s[colg]; cn[1] = cninv_s[16 + colg]; }
    else           { cn[0] = cninv[c0 + colg]; cn[1] = cninv[c0 + 16 + colg]; }

#pragma unroll
    for (int mf = 0; mf < 4; ++mf) {
#pragma unroll
        for (int r = 0; r < 4; ++r) {
            const int R = w8 * 64 + mf * 16 + rowg * 4 + r;
            const int labv = label[R];
            float s = 0.f;
            float sr;
            if (PASS == 2) sr = srow[R];
#pragma unroll
            for (int nf = 0; nf < 2; ++nf) {
                const int C = c0 + nf * 16 + colg;
                float x = acc[mf][nf][r] * cn[nf];   // 64*cos(theta)
                if (C == labv) {
                    float cs = fminf(1.f, fmaxf(-1.f, x * (1.0f / SCALE)));
                    x = SCALE * (cs * COS_M2 - sqrtf(fmaxf(0.f, 1.f - cs * cs)) * SIN_M2);
                }
                if (PASS == 1) {
                    s += exp2f(fmaf(x, LOG2E, -SHIFT64));
                } else {
                    out[(size_t)R * UNITS + C] = exp2f(fmaf(x, LOG2E, -sr));
                }
            }
            if (PASS == 1) {
                s += __shfl_xor(s, 1);
                s += __shfl_xor(s, 2);
                s += __shfl_xor(s, 4);
                s += __shfl_xor(s, 8);
                if (colg == 0) psum[blk * BATCH + R] = s;
            }
        }
    }
}

// ---------------- Kernel 3: column-sum psum[3125][512] -> partial[64][512] ------------
__global__ void colsum_k(const float* __restrict__ psum, float* __restrict__ partial) {
    const int g = blockIdx.x;    // 64
    const int t = threadIdx.x;   // 512
    const int b0 = g * 49;
    const int b1 = (b0 + 49 < NBLK) ? b0 + 49 : NBLK;
    float s = 0.f;
    for (int b = b0; b < b1; ++b) s += psum[b * BATCH + t];
    partial[g * BATCH + t] = s;
}

// ---------------- Kernel 4: srow[R] = 64*log2e + log2(total_R) ------------------------
__global__ void srow_k(const float* __restrict__ partial, float* __restrict__ srow) {
    const int t = threadIdx.x;   // 512
    float s = 0.f;
#pragma unroll
    for (int g = 0; g < 64; ++g) s += partial[g * BATCH + t];
    srow[t] = SHIFT64 + log2f(s);
}

extern "C" void kernel_launch(void* const* d_in, const int* in_sizes, int n_in,
                              void* d_out, int out_size, void* d_ws, size_t ws_size,
                              hipStream_t stream) {
    const float* inp   = (const float*)d_in[0];
    const int*   label = (const int*)d_in[1];
    const float* w     = (const float*)d_in[2];
    float* out = (float*)d_out;

    char* ws = (char*)d_ws;
    _Float16* A2   = (_Float16*)ws;                          // 512 KB
    float* cninv   = (float*)(ws + (1 << 20));               // 400 KB
    float* psum    = (float*)(ws + (2 << 20));               // 6.4 MB
    float* partial = (float*)(ws + (9 << 20));               // 128 KB
    float* srow    = (float*)(ws + (9 << 20) + (1 << 18));   // 2 KB

    norm_emb_k<<<BATCH, 64, 0, stream>>>(inp, A2);
    pass_k<1><<<NBLK, 512, 0, stream>>>(w, A2, label, cninv, srow, psum, out);
    colsum_k<<<64, 512, 0, stream>>>(psum, partial);
    srow_k<<<1, 512, 0, stream>>>(partial, srow);
    pass_k<2><<<NBLK, 512, 0, stream>>>(w, A2, label, cninv, srow, psum, out);
}

// Round 5
// 267.199 us; speedup vs baseline: 1.6590x; 1.6590x over previous
//
#include <hip/hip_runtime.h>
#include <math.h>

#define UNITS 100000
#define BATCH 512
#define DIM 512
#define BN 64
#define NBLK ((UNITS + BN - 1) / BN)   /* 1563 */
#define SCALE 64.0f
#define COS_M2 0.87758256189037271612f /* cos(0.5) */
#define SIN_M2 0.47942553860420300027f /* sin(0.5) */
#define LOG2E  1.44269504088896340736f

typedef _Float16 half8 __attribute__((ext_vector_type(8)));
typedef float floatx4 __attribute__((ext_vector_type(4)));

#define PHASE_BARRIER() do { \
    asm volatile("s_waitcnt lgkmcnt(0)" ::: "memory"); \
    __builtin_amdgcn_s_barrier(); \
} while (0)

// ---------------- Kernel 1: row-normalize inputs -> fragment-ordered fp16 A2 (x64) ----
__global__ void norm_emb_k(const float* __restrict__ inp, _Float16* __restrict__ A2) {
    const int row = blockIdx.x;
    const int lane = threadIdx.x;             // 64 threads = 1 wave
    const float* rp = inp + row * DIM + lane * 8;
    float v[8];
#pragma unroll
    for (int j = 0; j < 8; ++j) v[j] = rp[j];
    float ss = 0.f;
#pragma unroll
    for (int j = 0; j < 8; ++j) ss += v[j] * v[j];
#pragma unroll
    for (int off = 32; off > 0; off >>= 1) ss += __shfl_xor(ss, off);
    const float inv = SCALE / sqrtf(ss);      // fold s=64 into A
    half8 h;
#pragma unroll
    for (int j = 0; j < 8; ++j) h[j] = (_Float16)(v[j] * inv);
    const int idx = ((((row >> 4) * 16 + (lane >> 2)) * 64) + (row & 15) + 16 * (lane & 3)) * 8;
    *(half8*)(A2 + idx) = h;
}

// ---------------- Kernel 2: fused GEMM + col-norm + margin + tile-shifted exp ---------
// 8 waves, BN=64 cols, all 512 rows. K=512 as 8 chunks of 64, double-buffered LDS,
// raw barriers (lgkm only) so global loads stay in flight across phases.
template<bool HALF>
__global__ __launch_bounds__(512, 4) void gemmfused_k(
    const float* __restrict__ w, const _Float16* __restrict__ A2,
    const int* __restrict__ label,
    _Float16* __restrict__ vh, float* __restrict__ outf,
    float* __restrict__ psum, float* __restrict__ pmax) {
    __shared__ _Float16 Bt[2][512 * 8];      // 16 KB, granule = [kg][col] -> 8 halfs
    __shared__ float sqred[8][64];
    __shared__ float cninv_s[64];
    __shared__ float sums_s[512];
    __shared__ float maxs_s[512];

    const int t = threadIdx.x;
    const int blk = blockIdx.x;
    const int c0 = blk * BN;
    const int w8 = t >> 6;
    const int lane = t & 63;
    const int colg = lane & 15;
    const int rowg = lane >> 4;

    // staging: this thread owns col = lane, k-rows w8*8+i within each chunk
    const bool cval = (c0 + lane) < UNITS;
    const float* wbase = w + (cval ? (c0 + lane) : (UNITS - 1));

    float sq = 0.f;
    float rs[2][8];

    auto LOADC = [&](int ch, float* r) {
#pragma unroll
        for (int i = 0; i < 8; ++i)
            r[i] = wbase[(size_t)(ch * 64 + w8 * 8 + i) * UNITS];
    };
    auto WRITEC = [&](const float* r, int buf) {
        half8 h;
#pragma unroll
        for (int i = 0; i < 8; ++i) {
            const float x = cval ? r[i] : 0.f;
            sq += x * x;
            h[i] = (_Float16)x;
        }
        *(half8*)&Bt[buf][(w8 * 64 + lane) * 8] = h;
    };

    floatx4 acc[4][4];
#pragma unroll
    for (int mf = 0; mf < 4; ++mf)
#pragma unroll
        for (int nf = 0; nf < 4; ++nf) acc[mf][nf] = (floatx4){0.f, 0.f, 0.f, 0.f};

    auto MFMAC = [&](int ch, int buf) {
#pragma unroll
        for (int ksl = 0; ksl < 2; ++ksl) {
            half8 b[4];
#pragma unroll
            for (int nf = 0; nf < 4; ++nf)
                b[nf] = *(const half8*)&Bt[buf][((ksl * 4 + rowg) * 64 + nf * 16 + colg) * 8];
#pragma unroll
            for (int mf = 0; mf < 4; ++mf) {
                const half8 a = *(const half8*)(A2 +
                    (size_t)(((w8 * 4 + mf) * 16 + ch * 2 + ksl) * 64 + lane) * 8);
#pragma unroll
                for (int nf = 0; nf < 4; ++nf)
                    acc[mf][nf] = __builtin_amdgcn_mfma_f32_16x16x32_f16(a, b[nf], acc[mf][nf], 0, 0, 0);
            }
        }
    };

    // ---- pipelined staging + MFMA: phase ch loads ch+2, LDS-writes ch+1, MFMAs ch ----
    LOADC(0, rs[0]);
    LOADC(1, rs[1]);
    WRITEC(rs[0], 0);
    PHASE_BARRIER();
#pragma unroll
    for (int ch = 0; ch < 8; ++ch) {
        if (ch + 2 < 8) LOADC(ch + 2, rs[ch & 1]);
        if (ch + 1 < 8) WRITEC(rs[1 - (ch & 1)], (ch + 1) & 1);
        MFMAC(ch, ch & 1);
        PHASE_BARRIER();
    }

    // ---- column inv-norms (f32, per-block local) ----
    sqred[w8][lane] = sq;
    __syncthreads();
    if (t < 64) {
        float s = 0.f;
#pragma unroll
        for (int g = 0; g < 8; ++g) s += sqred[g][t];
        cninv_s[t] = rsqrtf(s);
    }
    __syncthreads();

    float cn[4];
#pragma unroll
    for (int nf = 0; nf < 4; ++nf) cn[nf] = cninv_s[nf * 16 + colg];

    // ---- epilogue: margin, per-(row,tile) shifted exp, bounce to LDS, coalesced vh ---
    _Float16* bounce = &Bt[0][0] + w8 * 1024;   // 16 rows x 64 cols fp16 per wave

#pragma unroll
    for (int mf = 0; mf < 4; ++mf) {
#pragma unroll
        for (int r = 0; r < 4; ++r) {
            const int R = w8 * 64 + mf * 16 + rowg * 4 + r;
            const int labv = label[R];
            float lg[4];
            float mx = -1e30f;
#pragma unroll
            for (int nf = 0; nf < 4; ++nf) {
                const int C = c0 + nf * 16 + colg;
                float x = acc[mf][nf][r] * cn[nf];   // 64*cos(theta)
                if (C == labv) {
                    float cs = fminf(1.f, fmaxf(-1.f, x * (1.0f / SCALE)));
                    x = SCALE * (cs * COS_M2 - sqrtf(fmaxf(0.f, 1.f - cs * cs)) * SIN_M2);
                }
                if (C >= UNITS) x = -1e30f;
                lg[nf] = x;
                mx = fmaxf(mx, x);
            }
            mx = fmaxf(mx, __shfl_xor(mx, 1));
            mx = fmaxf(mx, __shfl_xor(mx, 2));
            mx = fmaxf(mx, __shfl_xor(mx, 4));
            mx = fmaxf(mx, __shfl_xor(mx, 8));
            float s = 0.f;
#pragma unroll
            for (int nf = 0; nf < 4; ++nf) {
                const int C = c0 + nf * 16 + colg;
                const float e = exp2f((lg[nf] - mx) * LOG2E);
                s += (C < UNITS) ? e : 0.f;
                if (HALF) bounce[(rowg * 4 + r) * 64 + nf * 16 + colg] = (_Float16)e;
                else if (C < UNITS) outf[(size_t)R * UNITS + C] = e;
            }
            s += __shfl_xor(s, 1);
            s += __shfl_xor(s, 2);
            s += __shfl_xor(s, 4);
            s += __shfl_xor(s, 8);
            if (colg == 0) { sums_s[R] = s; maxs_s[R] = mx; }
        }
        if (HALF) {
            // wave-local readback (DS ops in-order per wave): 8 rows x 128B per store op
#pragma unroll
            for (int p = 0; p < 2; ++p) {
                const int row_l = p * 8 + (lane >> 3);
                const int seg = lane & 7;
                const half8 hv = *(const half8*)&bounce[row_l * 64 + seg * 8];
                const int gc = c0 + seg * 8;
                if (gc + 8 <= UNITS)
                    *(half8*)(vh + (size_t)(w8 * 64 + mf * 16 + row_l) * UNITS + gc) = hv;
            }
        }
    }

    // ---- coalesced psum/pmax block stores (kills 4B-scatter write inflation) ----
    __syncthreads();
    psum[(size_t)blk * BATCH + t] = sums_s[t];
    pmax[(size_t)blk * BATCH + t] = maxs_s[t];
}

// ---------------- Kernel 3: per-row global max + sum -> per-(row,tile) factor ---------
__global__ void rowfac_k(const float* __restrict__ psum, const float* __restrict__ pmax,
                         float* __restrict__ fac) {
    const int row = blockIdx.x;
    const int lane = threadIdx.x;   // 64
    float mx = -1e30f;
    for (int b = lane; b < NBLK; b += 64) mx = fmaxf(mx, pmax[(size_t)b * BATCH + row]);
#pragma unroll
    for (int off = 32; off > 0; off >>= 1) mx = fmaxf(mx, __shfl_xor(mx, off));
    float s = 0.f;
    for (int b = lane; b < NBLK; b += 64)
        s += psum[(size_t)b * BATCH + row] * exp2f((pmax[(size_t)b * BATCH + row] - mx) * LOG2E);
#pragma unroll
    for (int off = 32; off > 0; off >>= 1) s += __shfl_xor(s, off);
    const float invS = 1.0f / s;
    for (int b = lane; b < NBLK; b += 64)
        fac[(size_t)row * NBLK + b] = exp2f((pmax[(size_t)b * BATCH + row] - mx) * LOG2E) * invS;
}

// ---------------- Kernel 4: scale ----------------
__global__ void scale_half_k(const _Float16* __restrict__ v, const float* __restrict__ fac,
                             float* __restrict__ out) {
    const int row = blockIdx.y;
    const int c = (blockIdx.x * 256 + threadIdx.x) * 8;
    if (c >= UNITS) return;
    const float f = fac[(size_t)row * NBLK + (c >> 6)];
    const half8 h = *(const half8*)(v + (size_t)row * UNITS + c);
    float4 o1, o2;
    o1.x = (float)h[0] * f; o1.y = (float)h[1] * f; o1.z = (float)h[2] * f; o1.w = (float)h[3] * f;
    o2.x = (float)h[4] * f; o2.y = (float)h[5] * f; o2.z = (float)h[6] * f; o2.w = (float)h[7] * f;
    float* op = out + (size_t)row * UNITS + c;
    *(float4*)op = o1;
    *(float4*)(op + 4) = o2;
}

__global__ void scale_f32_k(float* __restrict__ out, const float* __restrict__ fac) {
    const int row = blockIdx.y;
    const int c = (blockIdx.x * 256 + threadIdx.x) * 8;
    if (c >= UNITS) return;
    const float f = fac[(size_t)row * NBLK + (c >> 6)];
    float* op = out + (size_t)row * UNITS + c;
    float4 o1 = *(float4*)op;
    float4 o2 = *(float4*)(op + 4);
    o1.x *= f; o1.y *= f; o1.z *= f; o1.w *= f;
    o2.x *= f; o2.y *= f; o2.z *= f; o2.w *= f;
    *(float4*)op = o1;
    *(float4*)(op + 4) = o2;
}

extern "C" void kernel_launch(void* const* d_in, const int* in_sizes, int n_in,
                              void* d_out, int out_size, void* d_ws, size_t ws_size,
                              hipStream_t stream) {
    const float* inp   = (const float*)d_in[0];
    const int*   label = (const int*)d_in[1];
    const float* w     = (const float*)d_in[2];
    float* out = (float*)d_out;

    char* ws = (char*)d_ws;
    _Float16* A2 = (_Float16*)ws;                 // 512 KB
    float* psum  = (float*)(ws + (4u << 20));     // 3.2 MB
    float* pmax  = (float*)(ws + (8u << 20));     // 3.2 MB
    float* fac   = (float*)(ws + (12u << 20));    // 3.2 MB
    _Float16* vh = (_Float16*)(ws + (16u << 20)); // 102.4 MB
    const size_t need = (size_t)(16u << 20) + (size_t)BATCH * UNITS * 2;
    const bool half_path = ws_size >= need;

    norm_emb_k<<<BATCH, 64, 0, stream>>>(inp, A2);
    if (half_path)
        gemmfused_k<true><<<NBLK, 512, 0, stream>>>(w, A2, label, vh, out, psum, pmax);
    else
        gemmfused_k<false><<<NBLK, 512, 0, stream>>>(w, A2, label, vh, out, psum, pmax);
    rowfac_k<<<BATCH, 64, 0, stream>>>(psum, pmax, fac);
    dim3 sg((UNITS + 2047) / 2048, BATCH);
    if (half_path)
        scale_half_k<<<sg, 256, 0, stream>>>(vh, fac, out);
    else
        scale_f32_k<<<sg, 256, 0, stream>>>(out, fac);
}